// Round 1
// 621.189 us; speedup vs baseline: 1.0994x; 1.0994x over previous
//
#include <hip/hip_runtime.h>
#include <hip/hip_bf16.h>
#include <type_traits>
#include <math.h>

// ---------------------------------------------------------------------------
// Attention: out = softmax_causal((x Wq^T + bq)(x Wk^T + bk)^T / sqrt(D)) (x Wv^T + bv) Wp^T + bp
// B=4, S=2048, D=2048, fp32 in/out, bf16 MFMA compute.
//
// R4: all GEMMs moved from the 128^2 2-barrier structure (~870 TF ceiling,
// MfmaUtil 40%) to the 256^2 8-phase counted-vmcnt template:
//   - 512 thr / 8 waves (2Mx4N), per-wave C = 128x64, acc[8][4] f32x4
//   - LDS 128 KiB: 2 dbuf x {A,B} x 2 halves of [128][64] bf16
//   - per K-tile: 4 phases x {ds_read subtile | 1 half-tile global_load_lds
//     | s_barrier | lgkmcnt(0)+sched_barrier | setprio(1) 16 MFMA setprio(0)
//     | s_barrier}; single s_waitcnt vmcnt(6) per K-tile (3 half-tiles in
//     flight survive the barrier) -- never vmcnt(0) in the main loop.
//   - stage/consume ledger: B halves are fully reg-consumed in phase 1 ->
//     restaged (tile+2, same buffer) at phases 2,3; A reads finish by phase 3
//     -> A0(tile+2) staged at phase 4; A1(tile+1) staged at phase 1 into the
//     other buffer. Prologue: tile0{A0,A1,B0,B1}+tile1{B0,B1,A0}, vmcnt(6).
//     Past-the-end prefetch wraps k mod Keff (lands in consumed regions).
//   - XOR slot swizzle (phys 16B slot p of row r holds logical p^(r&7))
//     kept from R3: staging picks swizzled GLOBAL column, reads XOR by fr&7.
//     Measured 0 bank conflicts.
//   - bijective XCD swizzle on the (x,y) grid (all grids %8==0).
//
// Workspace layout (256 MB):
//   [0,32)MB    xb    bf16 x              [8192,2048]
//   [32,56)MB   wqkv  bf16 [Wq;Wk;Wv]     [6144,2048]
//   [56,64)MB   wpb   bf16 Wp             [2048,2048]
//   [64,96)MB   qb    bf16 Q              (later reused as attn P)
//   [96,128)MB  kb    bf16 K              (later reused as ctx)
//   [160,192)MB vtb   bf16 V^T per batch  [B][D][S]
//   [192,256)MB sc    fp32 scores         [B,S,S]
// ---------------------------------------------------------------------------

typedef __bf16 bf16x8_t __attribute__((ext_vector_type(8)));
typedef float f32x4_t __attribute__((ext_vector_type(4)));
typedef unsigned short u16x8_t __attribute__((ext_vector_type(8)));

__device__ inline unsigned short f2bf(float f) {
  unsigned int u = __builtin_bit_cast(unsigned int, f);
  unsigned int r = u + 0x7fffu + ((u >> 16) & 1u);
  return (unsigned short)(r >> 16);
}

// async global->LDS, 16B per lane; lds dest = wave-uniform base + lane*16
__device__ inline void gl2lds16(const unsigned short* g, unsigned short* l) {
  __builtin_amdgcn_global_load_lds(
      (const __attribute__((address_space(1))) unsigned int*)g,
      (__attribute__((address_space(3))) unsigned int*)l, 16, 0, 0);
}

__device__ __forceinline__ bf16x8_t ldf(const unsigned short* p) {
  return __builtin_bit_cast(bf16x8_t, *(const u16x8_t*)p);
}

#define MF(a_, b_, c_) \
  (c_) = __builtin_amdgcn_mfma_f32_16x16x32_bf16((a_), (b_), (c_), 0, 0, 0)
#define FENCE() asm volatile("" ::: "memory")
#define BAR() __builtin_amdgcn_s_barrier()
#define LGK0() asm volatile("s_waitcnt lgkmcnt(0)" ::: "memory")
#define VM6() asm volatile("s_waitcnt vmcnt(6)" ::: "memory")
#define SCHED0() __builtin_amdgcn_sched_barrier(0)
#define PRIO(x) __builtin_amdgcn_s_setprio(x)

// ---------------- cast fp32 -> bf16 (x input) ------------------------------
__global__ __launch_bounds__(256) void cast_f32_bf16(
    const float* __restrict__ in, unsigned short* __restrict__ out, long n4) {
  long i = blockIdx.x * 256L + threadIdx.x;
  if (i >= n4) return;
  float4 f = ((const float4*)in)[i];
  ushort4 u;
  u.x = f2bf(f.x); u.y = f2bf(f.y); u.z = f2bf(f.z); u.w = f2bf(f.w);
  ((ushort4*)out)[i] = u;
}

// ---------------- fused 4-weight cast: blockIdx.y selects matrix -----------
__global__ __launch_bounds__(256) void cast_w4(
    const float* __restrict__ w0, const float* __restrict__ w1,
    const float* __restrict__ w2, const float* __restrict__ w3,
    unsigned short* __restrict__ o0, unsigned short* __restrict__ o1,
    unsigned short* __restrict__ o2, unsigned short* __restrict__ o3,
    long n4) {
  long i = blockIdx.x * 256L + threadIdx.x;
  if (i >= n4) return;
  const float* in; unsigned short* out;
  switch (blockIdx.y) {
    case 0: in = w0; out = o0; break;
    case 1: in = w1; out = o1; break;
    case 2: in = w2; out = o2; break;
    default: in = w3; out = o3; break;
  }
  float4 f = ((const float4*)in)[i];
  ushort4 u;
  u.x = f2bf(f.x); u.y = f2bf(f.y); u.z = f2bf(f.z); u.w = f2bf(f.w);
  ((ushort4*)out)[i] = u;
}

// ===================== 256^2 8-phase K-loop core ===========================
// A: [256 rows][K] at block row offset already applied; B likewise (NT form).
// LDS buffer (elems): buf b at b*32768; A0@0 A1@8192 B0@16384 B1@24576.
// Each half = [128 rows][64 cols] bf16, 16 KB; staged by 512 thr x 2 loads.
// Swizzle: phys 16B slot p of row r holds logical slot p^(r&7).
__device__ __forceinline__ void g256_kloop(
    const unsigned short* __restrict__ A, const unsigned short* __restrict__ B,
    int K, int Keff, unsigned short* smem, f32x4_t (&acc)[8][4]) {
  const int tid = threadIdx.x;
  const int lane = tid & 63;
  const int wave = tid >> 6;
  const int wr = wave >> 2;           // 0..1  (M half)
  const int wc = wave & 3;            // 0..3  (N quarter)
  const int fr = lane & 15;
  const int q4 = lane >> 4;
  const int s0 = (q4 ^ (fr & 7)) * 8;        // kk=0 swizzled slot
  const int s1 = ((q4 + 4) ^ (fr & 7)) * 8;  // kk=1 swizzled slot
  // staging: this thread's global offset (row + swizzled column)
  const size_t rowK =
      (size_t)(wave * 8 + (lane >> 3)) * (size_t)K +
      (size_t)(((lane & 7) ^ ((lane >> 3) & 7)) * 8);
  const size_t K64 = (size_t)64 * K;
  const size_t K128 = (size_t)128 * K;
  const int wofs = wave * 512;  // wave-uniform LDS chunk (1 KB)
  const int NT = Keff >> 6;

#define STG(gp_, lh_)                        \
  do {                                       \
    const unsigned short* g_ = (gp_) + rowK; \
    gl2lds16(g_, (lh_) + wofs);              \
    gl2lds16(g_ + K64, (lh_) + 4096 + wofs); \
  } while (0)

  // ---- prologue: tile0 {A0,A1,B0,B1} -> buf0; tile1 {B0,B1,A0} -> buf1 ----
  STG(A, smem);
  STG(A + K128, smem + 8192);
  STG(B, smem + 16384);
  STG(B + K128, smem + 24576);
  STG(B + 64, smem + 32768 + 16384);
  STG(B + K128 + 64, smem + 32768 + 24576);
  STG(A + 64, smem + 32768);
  VM6();   // tile0's 8 loads landed; tile1's {B0,B1,A0} (6 loads) in flight
  FENCE();
  BAR();

  for (int kt = 0; kt < NT; ++kt) {
    unsigned short* bc = smem + ((kt & 1) << 15);        // compute buffer
    unsigned short* nb = smem + (((kt + 1) & 1) << 15);  // other buffer
    const unsigned short* Ahc = bc + wr * 8192 + fr * 64;
    const unsigned short* Bhc =
        bc + 16384 + (wc >> 1) * 8192 + (wc & 1) * 4096 + fr * 64;
    int k1 = (kt + 1) << 6; if (k1 >= Keff) k1 -= Keff;  // wrap = safe garbage
    int k2 = (kt + 2) << 6; if (k2 >= Keff) k2 -= Keff;

    bf16x8_t bfr[4][2], af01[2][2], af25[4][2], af67[2][2];

    // ---------- phase 1: read all B + A m0,1; stage A1(kt+1) -> nb --------
#pragma unroll
    for (int n = 0; n < 4; ++n) {
      const unsigned short* p = Bhc + n * 1024;
      bfr[n][0] = ldf(p + s0);
      bfr[n][1] = ldf(p + s1);
    }
#pragma unroll
    for (int m = 0; m < 2; ++m) {
      const unsigned short* p = Ahc + m * 1024;
      af01[m][0] = ldf(p + s0);
      af01[m][1] = ldf(p + s1);
    }
    STG(A + K128 + k1, nb + 8192);
    FENCE(); BAR(); LGK0(); SCHED0();
    PRIO(1);
#pragma unroll
    for (int m = 0; m < 2; ++m)
#pragma unroll
      for (int n = 0; n < 4; ++n) {
        MF(af01[m][0], bfr[n][0], acc[m][n]);
        MF(af01[m][1], bfr[n][1], acc[m][n]);
      }
    PRIO(0);
    FENCE(); BAR();

    // ---------- phase 2: read A m2..5; stage B0(kt+2) -> bc (B reads done)-
#pragma unroll
    for (int m = 0; m < 4; ++m) {
      const unsigned short* p = Ahc + (m + 2) * 1024;
      af25[m][0] = ldf(p + s0);
      af25[m][1] = ldf(p + s1);
    }
    STG(B + k2, bc + 16384);
    FENCE(); BAR(); LGK0(); SCHED0();
    PRIO(1);
#pragma unroll
    for (int m = 0; m < 2; ++m)
#pragma unroll
      for (int n = 0; n < 4; ++n) {
        MF(af25[m][0], bfr[n][0], acc[2 + m][n]);
        MF(af25[m][1], bfr[n][1], acc[2 + m][n]);
      }
    PRIO(0);
    FENCE(); BAR();

    // ---------- phase 3: read A m6,7; stage B1(kt+2) -> bc ----------------
#pragma unroll
    for (int m = 0; m < 2; ++m) {
      const unsigned short* p = Ahc + (m + 6) * 1024;
      af67[m][0] = ldf(p + s0);
      af67[m][1] = ldf(p + s1);
    }
    STG(B + K128 + k2, bc + 24576);
    FENCE(); BAR(); LGK0(); SCHED0();
    PRIO(1);
#pragma unroll
    for (int m = 0; m < 2; ++m)
#pragma unroll
      for (int n = 0; n < 4; ++n) {
        MF(af25[2 + m][0], bfr[n][0], acc[4 + m][n]);
        MF(af25[2 + m][1], bfr[n][1], acc[4 + m][n]);
      }
    PRIO(0);
    FENCE(); BAR();

    // ---------- phase 4: stage A0(kt+2) -> bc (A reads done by ph3) -------
    STG(A + k2, bc);
    FENCE(); BAR(); LGK0(); SCHED0();
    PRIO(1);
#pragma unroll
    for (int m = 0; m < 2; ++m)
#pragma unroll
      for (int n = 0; n < 4; ++n) {
        MF(af67[m][0], bfr[n][0], acc[6 + m][n]);
        MF(af67[m][1], bfr[n][1], acc[6 + m][n]);
      }
    PRIO(0);
    VM6();  // leaves {B0,B1,A0}(kt+2) in flight; tile kt+1 fully landed
    FENCE(); BAR();
  }
#undef STG
}

// ---------------- generic NT GEMM (modes 0/1/2), 256^2 --------------------
// MODE 0: plain. MODE 1: causal block skip. MODE 2: causal K-limit.
template <int MODE, typename OutT>
__global__ __launch_bounds__(512, 2) void gemm256_nt(
    const unsigned short* __restrict__ A, const unsigned short* __restrict__ B,
    OutT* __restrict__ C, const float* __restrict__ bias, float alpha,
    int N, int K, size_t sA, size_t sB, size_t sC) {
  // bijective XCD swizzle (nwg % 8 == 0 for all launches)
  int lin = blockIdx.y * gridDim.x + blockIdx.x;
  const int nwg = gridDim.x * gridDim.y;
  lin = (lin & 7) * (nwg >> 3) + (lin >> 3);
  const int bm = (lin / gridDim.x) * 256;
  const int bn = (lin % gridDim.x) * 256;
  if (MODE == 1 && bn >= bm + 256) return;
  int Keff = K;
  if (MODE == 2) { int kl = bm + 256; Keff = kl < K ? kl : K; }

  A += (size_t)blockIdx.z * sA + (size_t)bm * K;
  B += (size_t)blockIdx.z * sB + (size_t)bn * K;
  C += (size_t)blockIdx.z * sC;

  __shared__ unsigned short smem[65536];  // 128 KiB
  f32x4_t acc[8][4] = {};
  g256_kloop(A, B, K, Keff, smem, acc);

  const int tid = threadIdx.x;
  const int lane = tid & 63;
  const int wave = tid >> 6;
  const int wr = wave >> 2, wc = wave & 3;
  const int fr = lane & 15, q4 = lane >> 4;
  const int r0 = bm + wr * 128 + q4 * 4;
  const int c0 = bn + wc * 64 + fr;
#pragma unroll
  for (int n = 0; n < 4; ++n) {
    const int col = c0 + n * 16;
    const float bs = bias ? bias[col] : 0.f;
#pragma unroll
    for (int m = 0; m < 8; ++m) {
      const int row = r0 + m * 16;
#pragma unroll
      for (int r = 0; r < 4; ++r) {
        float v = acc[m][n][r] * alpha + bs;
        if constexpr (std::is_same_v<OutT, float>)
          C[(size_t)(row + r) * N + col] = v;
        else
          C[(size_t)(row + r) * N + col] = f2bf(v);
      }
    }
  }
}

// ---------------- fused QKV GEMM: N = 3*D, triple-destination epilogue -----
__global__ __launch_bounds__(512, 2) void gemm256_qkv(
    const unsigned short* __restrict__ A, const unsigned short* __restrict__ Bw,
    unsigned short* __restrict__ Q, unsigned short* __restrict__ Kd,
    unsigned short* __restrict__ Vt,
    const float* __restrict__ bq, const float* __restrict__ bk,
    const float* __restrict__ bv, int K, int D, int S) {
  int lin = blockIdx.y * gridDim.x + blockIdx.x;
  const int nwg = gridDim.x * gridDim.y;
  lin = (lin & 7) * (nwg >> 3) + (lin >> 3);
  const int bm = (lin / gridDim.x) * 256;
  const int bn = (lin % gridDim.x) * 256;

  __shared__ unsigned short smem[65536];
  f32x4_t acc[8][4] = {};
  g256_kloop(A + (size_t)bm * K, Bw + (size_t)bn * K, K, K, smem, acc);

  const int tid = threadIdx.x;
  const int lane = tid & 63;
  const int wave = tid >> 6;
  const int wr = wave >> 2, wc = wave & 3;
  const int fr = lane & 15, q4 = lane >> 4;
  const int r0 = bm + wr * 128 + q4 * 4;
  const int c0 = bn + wc * 64 + fr;
#pragma unroll
  for (int n = 0; n < 4; ++n) {
    const int col = c0 + n * 16;              // [0, 3D)
    const int sel = col >> 11;                // 0:Q 1:K 2:V (D=2048)
    const int idx = col & (D - 1);
    const float bs = (sel == 0 ? bq : sel == 1 ? bk : bv)[idx];
#pragma unroll
    for (int m = 0; m < 8; ++m) {
      const int row = r0 + m * 16;
      if (sel < 2) {
        unsigned short* dst = sel == 0 ? Q : Kd;
#pragma unroll
        for (int r = 0; r < 4; ++r)
          dst[(size_t)(row + r) * D + idx] = f2bf(acc[m][n][r] + bs);
      } else {
        const int b = row >> 11;              // S=2048
        const int s = row & (S - 1);          // multiple of 4
        ushort4 pack;
        pack.x = f2bf(acc[m][n][0] + bs);
        pack.y = f2bf(acc[m][n][1] + bs);
        pack.z = f2bf(acc[m][n][2] + bs);
        pack.w = f2bf(acc[m][n][3] + bs);
        *(ushort4*)&Vt[(size_t)b * D * S + (size_t)idx * S + s] = pack;
      }
    }
  }
}

// ---------------- causal softmax: fp32 scores row -> bf16 attn row ----------
__global__ __launch_bounds__(256) void softmax_causal(
    const float* __restrict__ Sc, unsigned short* __restrict__ P, int n) {
  const int row = blockIdx.x;
  const int q = row & (n - 1);
  const float* srow = Sc + (size_t)row * n;
  unsigned short* prow = P + (size_t)row * n;
  const int tid = threadIdx.x, lane = tid & 63, wid = tid >> 6;
  __shared__ float red[4];

  float m = -3.0e38f;
  for (int j = tid; j <= q; j += 256) m = fmaxf(m, srow[j]);
#pragma unroll
  for (int o = 32; o; o >>= 1) m = fmaxf(m, __shfl_down(m, o, 64));
  if (lane == 0) red[wid] = m;
  __syncthreads();
  m = fmaxf(fmaxf(red[0], red[1]), fmaxf(red[2], red[3]));
  __syncthreads();

  float s = 0.f;
  for (int j = tid; j <= q; j += 256) s += __expf(srow[j] - m);
#pragma unroll
  for (int o = 32; o; o >>= 1) s += __shfl_down(s, o, 64);
  if (lane == 0) red[wid] = s;
  __syncthreads();
  s = red[0] + red[1] + red[2] + red[3];
  const float inv = 1.f / s;

  for (int j = tid; j < n; j += 256) {
    float v = (j <= q) ? __expf(srow[j] - m) * inv : 0.f;
    prow[j] = f2bf(v);
  }
}

// ---------------------------------------------------------------------------
extern "C" void kernel_launch(void* const* d_in, const int* in_sizes, int n_in,
                              void* d_out, int out_size, void* d_ws, size_t ws_size,
                              hipStream_t stream) {
  const int B = 4, S = 2048, D = 2048;
  const int M = B * S;  // 8192

  const float* x  = (const float*)d_in[0];
  // d_in[1] = mask: guaranteed causal tril, hardcoded in kernels
  const float* Wq = (const float*)d_in[2];
  const float* bq = (const float*)d_in[3];
  const float* Wk = (const float*)d_in[4];
  const float* bk = (const float*)d_in[5];
  const float* Wv = (const float*)d_in[6];
  const float* bv = (const float*)d_in[7];
  const float* Wp = (const float*)d_in[8];
  const float* bp = (const float*)d_in[9];
  float* out = (float*)d_out;

  char* ws = (char*)d_ws;
  const size_t MB = 1ull << 20;
  unsigned short* xb   = (unsigned short*)(ws + 0);
  unsigned short* wqkv = (unsigned short*)(ws + 32 * MB);  // [6144,2048]
  unsigned short* wpb  = (unsigned short*)(ws + 56 * MB);
  unsigned short* qb   = (unsigned short*)(ws + 64 * MB);
  unsigned short* kb   = (unsigned short*)(ws + 96 * MB);
  unsigned short* vtb  = (unsigned short*)(ws + 160 * MB);
  float*          sc   = (float*)(ws + 192 * MB);
  unsigned short* pb   = qb;  // attn reuses Q (dead after scores GEMM)
  unsigned short* cb   = kb;  // ctx reuses K (dead after scores GEMM)

  const long nx = (long)M * D;
  const long nw = (long)D * D;

  // 1) casts: x, then all 4 weights in one launch (into stacked layout)
  cast_f32_bf16<<<dim3((unsigned)((nx / 4 + 255) / 256)), 256, 0, stream>>>(x, xb, nx / 4);
  cast_w4<<<dim3((unsigned)((nw / 4 + 255) / 256), 4), 256, 0, stream>>>(
      Wq, Wk, Wv, Wp,
      wqkv, wqkv + (size_t)D * D, wqkv + 2 * (size_t)D * D, wpb, nw / 4);

  const dim3 blk(512);

  // 2) fused QKV projection (N=6144, 768 blocks); V written transposed
  gemm256_qkv<<<dim3(3 * D / 256, M / 256), blk, 0, stream>>>(
      xb, wqkv, qb, kb, vtb, bq, bk, bv, D, D, S);

  // 3) scores = Q K^T * inv_std (fp32 out, causal block skip)
  const float inv_std = 1.f / sqrtf((float)D);
  gemm256_nt<1, float><<<dim3(S / 256, S / 256, B), blk, 0, stream>>>(
      qb, kb, sc, nullptr, inv_std, S, D, (size_t)S * D, (size_t)S * D, (size_t)S * S);

  // 4) causal softmax -> bf16 attn
  softmax_causal<<<dim3(B * S), dim3(256), 0, stream>>>(sc, pb, S);

  // 5) ctx = attn @ V  (via V^T, NT form; K-range capped at diagonal)
  gemm256_nt<2, unsigned short><<<dim3(D / 256, S / 256, B), blk, 0, stream>>>(
      pb, vtb, cb, nullptr, 1.f, D, S, (size_t)S * S, (size_t)D * S, (size_t)S * D);

  // 6) out = ctx Wp^T + bp (fp32 out)
  gemm256_nt<0, float><<<dim3(D / 256, M / 256), blk, 0, stream>>>(
      cb, wpb, out, bp, 1.f, D, D, 0, 0, 0);
}

// Round 3
// 599.005 us; speedup vs baseline: 1.1401x; 1.0370x over previous
//
#include <hip/hip_runtime.h>
#include <hip/hip_bf16.h>
#include <type_traits>
#include <math.h>

// ---------------------------------------------------------------------------
// Attention: out = softmax_causal((x Wq^T + bq)(x Wk^T + bk)^T / sqrt(D)) (x Wv^T + bv) Wp^T + bp
// B=4, S=2048, D=2048, fp32 in/out, bf16 MFMA compute.
//
// R6 = R5 with the phase-4 correctness fix. R5's bug: ph4 overwrote bfr with
// the NEXT tile's B fragments BEFORE MFMA m6,7 consumed the current tile's
// bfr -> m67 used wrong B (absmax 1.17). Fix: in-place per-slice rotation --
// consume bfr[n] (4 MFMAs) then immediately refill bfr[n] from the next
// buffer (WAR-ordered, zero extra registers). All refills sit after the
// vmcnt(4)+barrier gate, so tile kt+1 data has landed globally.
//
// Schedule per K-tile (4 phases, reg-fragments pipelined one phase ahead):
//   ph1{rd a23 | STG A1(kt+1)->nb | BAR | MFMA m01 | BAR}
//   ph2{rd a45 | STG B0(kt+2)->bc | BAR | MFMA m23 | BAR}
//   ph3{rd a67 | STG B1(kt+2)->bc | BAR | MFMA m45 | BAR}
//   ph4{vmcnt(4); lgkmcnt(0); BAR | STG A0(kt+2)->bc |
//       interleaved: 4x{MFMA m67 slice n; refill bfr[n] from nb} |
//       rd a01(next) | BAR}
// Safety ledger (cross-wave):
//   - ph4's vmcnt(4)+BAR: ALL waves' tile-(kt+1) loads landed before the nb
//     reads (vmcnt is per-wave; the barrier globalizes it).
//   - ph4's lgkmcnt(0)+BAR: every wave's bc A-reads (a23/a45/a67) drained,
//     so the post-barrier STG A0 cannot overwrite rows still being read.
//   - B0/B1 restage at ph2/ph3: all bfr reads of bc B complete before ph1's
//     MFMA m01 (operand wait), hence before ph1's closing barrier.
//   - A1 restage at ph1: prior tile's a67 reads drained at prev ph4's
//     lgkmcnt(0)+BAR.
// vmcnt ledger: carried-in 6 {B0,B1,A0}(kt+1); +A1@ph1 +B0@ph2 +B1@ph3 = 12;
// vmcnt(4) lands oldest 8 = tile kt+1 complete; +A0@ph4 -> carried 6. Wrapped
// k mod Keff past-the-end prefetch lands only in consumed regions.
// XOR slot swizzle (phys 16B slot p of row r holds logical p^(r&7)) kept
// (0 bank conflicts measured). Bijective XCD swizzle kept (grids %8==0).
//
// Workspace layout (256 MB):
//   [0,32)MB    xb    bf16 x              [8192,2048]
//   [32,56)MB   wqkv  bf16 [Wq;Wk;Wv]     [6144,2048]
//   [56,64)MB   wpb   bf16 Wp             [2048,2048]
//   [64,96)MB   qb    bf16 Q              (later reused as attn P)
//   [96,128)MB  kb    bf16 K              (later reused as ctx)
//   [160,192)MB vtb   bf16 V^T per batch  [B][D][S]
//   [192,256)MB sc    fp32 scores         [B,S,S]
// ---------------------------------------------------------------------------

typedef __bf16 bf16x8_t __attribute__((ext_vector_type(8)));
typedef float f32x4_t __attribute__((ext_vector_type(4)));
typedef unsigned short u16x8_t __attribute__((ext_vector_type(8)));

__device__ inline unsigned short f2bf(float f) {
  unsigned int u = __builtin_bit_cast(unsigned int, f);
  unsigned int r = u + 0x7fffu + ((u >> 16) & 1u);
  return (unsigned short)(r >> 16);
}

// async global->LDS, 16B per lane; lds dest = wave-uniform base + lane*16
__device__ inline void gl2lds16(const unsigned short* g, unsigned short* l) {
  __builtin_amdgcn_global_load_lds(
      (const __attribute__((address_space(1))) unsigned int*)g,
      (__attribute__((address_space(3))) unsigned int*)l, 16, 0, 0);
}

__device__ __forceinline__ bf16x8_t ldf(const unsigned short* p) {
  return __builtin_bit_cast(bf16x8_t, *(const u16x8_t*)p);
}

#define MF(a_, b_, c_) \
  (c_) = __builtin_amdgcn_mfma_f32_16x16x32_bf16((a_), (b_), (c_), 0, 0, 0)
#define FENCE() asm volatile("" ::: "memory")
#define BARF()              \
  do {                      \
    FENCE();                \
    __builtin_amdgcn_s_barrier(); \
    FENCE();                \
  } while (0)
#define LGK0() asm volatile("s_waitcnt lgkmcnt(0)" ::: "memory")
#define VM4() asm volatile("s_waitcnt vmcnt(4)" ::: "memory")
#define VM6() asm volatile("s_waitcnt vmcnt(6)" ::: "memory")
#define PRIO(x) __builtin_amdgcn_s_setprio(x)

// ---------------- cast fp32 -> bf16 (x input) ------------------------------
__global__ __launch_bounds__(256) void cast_f32_bf16(
    const float* __restrict__ in, unsigned short* __restrict__ out, long n4) {
  long i = blockIdx.x * 256L + threadIdx.x;
  if (i >= n4) return;
  float4 f = ((const float4*)in)[i];
  ushort4 u;
  u.x = f2bf(f.x); u.y = f2bf(f.y); u.z = f2bf(f.z); u.w = f2bf(f.w);
  ((ushort4*)out)[i] = u;
}

// ---------------- fused 4-weight cast: blockIdx.y selects matrix -----------
__global__ __launch_bounds__(256) void cast_w4(
    const float* __restrict__ w0, const float* __restrict__ w1,
    const float* __restrict__ w2, const float* __restrict__ w3,
    unsigned short* __restrict__ o0, unsigned short* __restrict__ o1,
    unsigned short* __restrict__ o2, unsigned short* __restrict__ o3,
    long n4) {
  long i = blockIdx.x * 256L + threadIdx.x;
  if (i >= n4) return;
  const float* in; unsigned short* out;
  switch (blockIdx.y) {
    case 0: in = w0; out = o0; break;
    case 1: in = w1; out = o1; break;
    case 2: in = w2; out = o2; break;
    default: in = w3; out = o3; break;
  }
  float4 f = ((const float4*)in)[i];
  ushort4 u;
  u.x = f2bf(f.x); u.y = f2bf(f.y); u.z = f2bf(f.z); u.w = f2bf(f.w);
  ((ushort4*)out)[i] = u;
}

// ===================== 256^2 pipelined 4-phase K-loop ======================
// LDS buffer (elems): buf b at b*32768; A0@0 A1@8192 B0@16384 B1@24576.
// Each half = [128 rows][64 cols] bf16, 16 KB; staged by 512 thr x 2 loads.
__device__ __forceinline__ void g256_kloop(
    const unsigned short* __restrict__ A, const unsigned short* __restrict__ B,
    int K, int Keff, unsigned short* smem, f32x4_t (&acc)[8][4]) {
  const int tid = threadIdx.x;
  const int lane = tid & 63;
  const int wave = tid >> 6;
  const int wr = wave >> 2;           // 0..1  (M half)
  const int wc = wave & 3;            // 0..3  (N quarter)
  const int fr = lane & 15;
  const int q4 = lane >> 4;
  const int s0 = (q4 ^ (fr & 7)) * 8;        // kk=0 swizzled slot
  const int s1 = ((q4 + 4) ^ (fr & 7)) * 8;  // kk=1 swizzled slot
  // staging: this thread's global offset (row + swizzled column)
  const size_t rowK =
      (size_t)(wave * 8 + (lane >> 3)) * (size_t)K +
      (size_t)(((lane & 7) ^ ((lane >> 3) & 7)) * 8);
  const size_t K64 = (size_t)64 * K;
  const size_t K128 = (size_t)128 * K;
  const int wofs = wave * 512;  // wave-uniform LDS chunk (1 KB)
  const int NT = Keff >> 6;     // always >= 4 here
  const int aoff = wr * 8192 + fr * 64;
  const int boff = 16384 + (wc >> 1) * 8192 + (wc & 1) * 4096 + fr * 64;

#define STG(gp_, lh_)                        \
  do {                                       \
    const unsigned short* g_ = (gp_) + rowK; \
    gl2lds16(g_, (lh_) + wofs);              \
    gl2lds16(g_ + K64, (lh_) + 4096 + wofs); \
  } while (0)

#define MFMA8(mb_, af_)                          \
  _Pragma("unroll")                              \
  for (int n = 0; n < 4; ++n) {                  \
    MF(af_[0][0], bfr[n][0], acc[(mb_)][n]);     \
    MF(af_[0][1], bfr[n][1], acc[(mb_)][n]);     \
    MF(af_[1][0], bfr[n][0], acc[(mb_) + 1][n]); \
    MF(af_[1][1], bfr[n][1], acc[(mb_) + 1][n]); \
  }

#define RDA(dst_, base_, mo_)                          \
  _Pragma("unroll")                                    \
  for (int m = 0; m < 2; ++m) {                        \
    dst_[m][0] = ldf((base_) + (m + (mo_)) * 1024 + s0); \
    dst_[m][1] = ldf((base_) + (m + (mo_)) * 1024 + s1); \
  }

  // ---- prologue: tile0 {A0,A1,B0,B1} -> buf0; tile1 {B0,B1,A0} -> buf1 ----
  STG(A, smem);
  STG(A + K128, smem + 8192);
  STG(B, smem + 16384);
  STG(B + K128, smem + 24576);
  STG(B + 64, smem + 32768 + 16384);
  STG(B + K128 + 64, smem + 32768 + 24576);
  STG(A + 64, smem + 32768);
  VM6();   // tile0's 8 loads landed (per-wave); 6 in flight for tile1
  BARF();  // now landed for ALL waves

  bf16x8_t bfr[4][2], a01[2][2], a23[2][2], a45[2][2], a67[2][2];
  {  // tile0 phase-1 fragments
    const unsigned short* Bh = smem + boff;
    const unsigned short* Ah = smem + aoff;
#pragma unroll
    for (int n = 0; n < 4; ++n) {
      bfr[n][0] = ldf(Bh + n * 1024 + s0);
      bfr[n][1] = ldf(Bh + n * 1024 + s1);
    }
    RDA(a01, Ah, 0);
  }

  for (int kt = 0; kt < NT; ++kt) {
    unsigned short* bc = smem + ((kt & 1) << 15);        // compute buffer
    unsigned short* nb = smem + (((kt + 1) & 1) << 15);  // next buffer
    const unsigned short* Ahc = bc + aoff;
    const unsigned short* Ahn = nb + aoff;
    const unsigned short* Bhn = nb + boff;
    int k1 = (kt + 1) << 6; if (k1 >= Keff) k1 -= Keff;  // wrap = safe garbage
    int k2 = (kt + 2) << 6; if (k2 >= Keff) k2 -= Keff;

    // ---- phase 1: rd a23 (for ph2); STG A1(kt+1)->nb; MFMA m0,1 ----------
    RDA(a23, Ahc, 2);
    STG(A + K128 + k1, nb + 8192);
    BARF();
    PRIO(1);
    MFMA8(0, a01);
    PRIO(0);
    BARF();

    // ---- phase 2: rd a45; STG B0(kt+2)->bc; MFMA m2,3 --------------------
    RDA(a45, Ahc, 4);
    STG(B + k2, bc + 16384);
    BARF();
    PRIO(1);
    MFMA8(2, a23);
    PRIO(0);
    BARF();

    // ---- phase 3: rd a67; STG B1(kt+2)->bc; MFMA m4,5 --------------------
    RDA(a67, Ahc, 6);
    STG(B + K128 + k2, bc + 24576);
    BARF();
    PRIO(1);
    MFMA8(4, a45);
    PRIO(0);
    BARF();

    // ---- phase 4: gate; STG A0(kt+2); MFMA m6,7 with in-place bfr rotate -
    VM4();   // tile kt+1 fully landed (per-wave): oldest 8 of 12
    LGK0();  // own bc A-reads drained -> post-barrier STG A0 cross-wave safe
    BARF();  // global: tile kt+1 landed everywhere; all bc A-reads done
    STG(A + k2, bc);
    PRIO(1);
#pragma unroll
    for (int n = 0; n < 4; ++n) {
      // consume bfr[n] (tile kt) ...
      MF(a67[0][0], bfr[n][0], acc[6][n]);
      MF(a67[0][1], bfr[n][1], acc[6][n]);
      MF(a67[1][0], bfr[n][0], acc[7][n]);
      MF(a67[1][1], bfr[n][1], acc[7][n]);
      // ... then refill with tile kt+1 (WAR-ordered after the 4 MFMAs)
      bfr[n][0] = ldf(Bhn + n * 1024 + s0);
      bfr[n][1] = ldf(Bhn + n * 1024 + s1);
    }
    RDA(a01, Ahn, 0);
    PRIO(0);
    BARF();
  }
#undef STG
#undef MFMA8
#undef RDA
}

// ---------------- generic NT GEMM (modes 0/1/2), 256^2 --------------------
// MODE 0: plain. MODE 1: causal block skip. MODE 2: causal K-limit.
template <int MODE, typename OutT>
__global__ __launch_bounds__(512, 2) void gemm256_nt(
    const unsigned short* __restrict__ A, const unsigned short* __restrict__ B,
    OutT* __restrict__ C, const float* __restrict__ bias, float alpha,
    int N, int K, size_t sA, size_t sB, size_t sC) {
  // bijective XCD swizzle (nwg % 8 == 0 for all launches)
  int lin = blockIdx.y * gridDim.x + blockIdx.x;
  const int nwg = gridDim.x * gridDim.y;
  lin = (lin & 7) * (nwg >> 3) + (lin >> 3);
  const int bm = (lin / gridDim.x) * 256;
  const int bn = (lin % gridDim.x) * 256;
  if (MODE == 1 && bn >= bm + 256) return;
  int Keff = K;
  if (MODE == 2) { int kl = bm + 256; Keff = kl < K ? kl : K; }

  A += (size_t)blockIdx.z * sA + (size_t)bm * K;
  B += (size_t)blockIdx.z * sB + (size_t)bn * K;
  C += (size_t)blockIdx.z * sC;

  __shared__ unsigned short smem[65536];  // 128 KiB
  f32x4_t acc[8][4] = {};
  g256_kloop(A, B, K, Keff, smem, acc);

  const int tid = threadIdx.x;
  const int lane = tid & 63;
  const int wave = tid >> 6;
  const int wr = wave >> 2, wc = wave & 3;
  const int fr = lane & 15, q4 = lane >> 4;
  const int r0 = bm + wr * 128 + q4 * 4;
  const int c0 = bn + wc * 64 + fr;
#pragma unroll
  for (int n = 0; n < 4; ++n) {
    const int col = c0 + n * 16;
    const float bs = bias ? bias[col] : 0.f;
#pragma unroll
    for (int m = 0; m < 8; ++m) {
      const int row = r0 + m * 16;
#pragma unroll
      for (int r = 0; r < 4; ++r) {
        float v = acc[m][n][r] * alpha + bs;
        if constexpr (std::is_same_v<OutT, float>)
          C[(size_t)(row + r) * N + col] = v;
        else
          C[(size_t)(row + r) * N + col] = f2bf(v);
      }
    }
  }
}

// ---------------- fused QKV GEMM: N = 3*D, triple-destination epilogue -----
__global__ __launch_bounds__(512, 2) void gemm256_qkv(
    const unsigned short* __restrict__ A, const unsigned short* __restrict__ Bw,
    unsigned short* __restrict__ Q, unsigned short* __restrict__ Kd,
    unsigned short* __restrict__ Vt,
    const float* __restrict__ bq, const float* __restrict__ bk,
    const float* __restrict__ bv, int K, int D, int S) {
  int lin = blockIdx.y * gridDim.x + blockIdx.x;
  const int nwg = gridDim.x * gridDim.y;
  lin = (lin & 7) * (nwg >> 3) + (lin >> 3);
  const int bm = (lin / gridDim.x) * 256;
  const int bn = (lin % gridDim.x) * 256;

  __shared__ unsigned short smem[65536];
  f32x4_t acc[8][4] = {};
  g256_kloop(A + (size_t)bm * K, Bw + (size_t)bn * K, K, K, smem, acc);

  const int tid = threadIdx.x;
  const int lane = tid & 63;
  const int wave = tid >> 6;
  const int wr = wave >> 2, wc = wave & 3;
  const int fr = lane & 15, q4 = lane >> 4;
  const int r0 = bm + wr * 128 + q4 * 4;
  const int c0 = bn + wc * 64 + fr;
#pragma unroll
  for (int n = 0; n < 4; ++n) {
    const int col = c0 + n * 16;              // [0, 3D)
    const int sel = col >> 11;                // 0:Q 1:K 2:V (D=2048)
    const int idx = col & (D - 1);
    const float bs = (sel == 0 ? bq : sel == 1 ? bk : bv)[idx];
#pragma unroll
    for (int m = 0; m < 8; ++m) {
      const int row = r0 + m * 16;
      if (sel < 2) {
        unsigned short* dst = sel == 0 ? Q : Kd;
#pragma unroll
        for (int r = 0; r < 4; ++r)
          dst[(size_t)(row + r) * D + idx] = f2bf(acc[m][n][r] + bs);
      } else {
        const int b = row >> 11;              // S=2048
        const int s = row & (S - 1);          // multiple of 4
        ushort4 pack;
        pack.x = f2bf(acc[m][n][0] + bs);
        pack.y = f2bf(acc[m][n][1] + bs);
        pack.z = f2bf(acc[m][n][2] + bs);
        pack.w = f2bf(acc[m][n][3] + bs);
        *(ushort4*)&Vt[(size_t)b * D * S + (size_t)idx * S + s] = pack;
      }
    }
  }
}

// ---------------- causal softmax: fp32 scores row -> bf16 attn row ----------
__global__ __launch_bounds__(256) void softmax_causal(
    const float* __restrict__ Sc, unsigned short* __restrict__ P, int n) {
  const int row = blockIdx.x;
  const int q = row & (n - 1);
  const float* srow = Sc + (size_t)row * n;
  unsigned short* prow = P + (size_t)row * n;
  const int tid = threadIdx.x, lane = tid & 63, wid = tid >> 6;
  __shared__ float red[4];

  float m = -3.0e38f;
  for (int j = tid; j <= q; j += 256) m = fmaxf(m, srow[j]);
#pragma unroll
  for (int o = 32; o; o >>= 1) m = fmaxf(m, __shfl_down(m, o, 64));
  if (lane == 0) red[wid] = m;
  __syncthreads();
  m = fmaxf(fmaxf(red[0], red[1]), fmaxf(red[2], red[3]));
  __syncthreads();

  float s = 0.f;
  for (int j = tid; j <= q; j += 256) s += __expf(srow[j] - m);
#pragma unroll
  for (int o = 32; o; o >>= 1) s += __shfl_down(s, o, 64);
  if (lane == 0) red[wid] = s;
  __syncthreads();
  s = red[0] + red[1] + red[2] + red[3];
  const float inv = 1.f / s;

  for (int j = tid; j < n; j += 256) {
    float v = (j <= q) ? __expf(srow[j] - m) * inv : 0.f;
    prow[j] = f2bf(v);
  }
}

// ---------------------------------------------------------------------------
extern "C" void kernel_launch(void* const* d_in, const int* in_sizes, int n_in,
                              void* d_out, int out_size, void* d_ws, size_t ws_size,
                              hipStream_t stream) {
  const int B = 4, S = 2048, D = 2048;
  const int M = B * S;  // 8192

  const float* x  = (const float*)d_in[0];
  // d_in[1] = mask: guaranteed causal tril, hardcoded in kernels
  const float* Wq = (const float*)d_in[2];
  const float* bq = (const float*)d_in[3];
  const float* Wk = (const float*)d_in[4];
  const float* bk = (const float*)d_in[5];
  const float* Wv = (const float*)d_in[6];
  const float* bv = (const float*)d_in[7];
  const float* Wp = (const float*)d_in[8];
  const float* bp = (const float*)d_in[9];
  float* out = (float*)d_out;

  char* ws = (char*)d_ws;
  const size_t MB = 1ull << 20;
  unsigned short* xb   = (unsigned short*)(ws + 0);
  unsigned short* wqkv = (unsigned short*)(ws + 32 * MB);  // [6144,2048]
  unsigned short* wpb  = (unsigned short*)(ws + 56 * MB);
  unsigned short* qb   = (unsigned short*)(ws + 64 * MB);
  unsigned short* kb   = (unsigned short*)(ws + 96 * MB);
  unsigned short* vtb  = (unsigned short*)(ws + 160 * MB);
  float*          sc   = (float*)(ws + 192 * MB);
  unsigned short* pb   = qb;  // attn reuses Q (dead after scores GEMM)
  unsigned short* cb   = kb;  // ctx reuses K (dead after scores GEMM)

  const long nx = (long)M * D;
  const long nw = (long)D * D;

  // 1) casts: x, then all 4 weights in one launch (into stacked layout)
  cast_f32_bf16<<<dim3((unsigned)((nx / 4 + 255) / 256)), 256, 0, stream>>>(x, xb, nx / 4);
  cast_w4<<<dim3((unsigned)((nw / 4 + 255) / 256), 4), 256, 0, stream>>>(
      Wq, Wk, Wv, Wp,
      wqkv, wqkv + (size_t)D * D, wqkv + 2 * (size_t)D * D, wpb, nw / 4);

  const dim3 blk(512);

  // 2) fused QKV projection (N=6144, 768 blocks); V written transposed
  gemm256_qkv<<<dim3(3 * D / 256, M / 256), blk, 0, stream>>>(
      xb, wqkv, qb, kb, vtb, bq, bk, bv, D, D, S);

  // 3) scores = Q K^T * inv_std (fp32 out, causal block skip)
  const float inv_std = 1.f / sqrtf((float)D);
  gemm256_nt<1, float><<<dim3(S / 256, S / 256, B), blk, 0, stream>>>(
      qb, kb, sc, nullptr, inv_std, S, D, (size_t)S * D, (size_t)S * D, (size_t)S * S);

  // 4) causal softmax -> bf16 attn
  softmax_causal<<<dim3(B * S), dim3(256), 0, stream>>>(sc, pb, S);

  // 5) ctx = attn @ V  (via V^T, NT form; K-range capped at diagonal)
  gemm256_nt<2, unsigned short><<<dim3(D / 256, S / 256, B), blk, 0, stream>>>(
      pb, vtb, cb, nullptr, 1.f, D, S, (size_t)S * S, (size_t)D * S, (size_t)S * D);

  // 6) out = ctx Wp^T + bp (fp32 out)
  gemm256_nt<0, float><<<dim3(D / 256, M / 256), blk, 0, stream>>>(
      cb, wpb, out, bp, 1.f, D, D, 0, 0, 0);
}